// Round 11
// baseline (333.968 us; speedup 1.0000x reference)
//
#include <hip/hip_runtime.h>

// SNN spike layer: causal alpha-PSP FIR conv (taps 1..76; srm[0]==0 exactly)
// + sequential refractory threshold scan.
//
// Round-11: DECOUPLED conv/scan via an exact theorem. The refractory kernel
// is strictly non-positive (mult = -SCALE_REF*THETA = -20, alpha >= 0), so
// pend <= 0 and u_eff = u + pend <= u. Hence if u[t] < theta for ALL t of a
// row, no spike ever fires -- exactly, independent of history. The conv is
// feed-forward, so it parallelizes over time freely; only rows where u
// crosses theta anywhere need the sequential scan.
//   dispatch 1: memset per-neuron flags (256 KB ws)
//   dispatch 2 (K1): thread=(neuron, chunk-of-20), grid.y=15 -> 983k threads
//     = 15 waves/SIMD offered (vs the 10-round structural wall of 1).
//     Dense banded conv from global (all float4 windows 16B-aligned;
//     ch-uniform scalar guards for t<0). Identical ascending-j fmaf chain
//     as every verified round -> u bit-identical. any(u>=theta) -> atomicOr
//     flag (never taken for this input class -> no contention). Store zeros.
//   dispatch 3 (K2): 1 thread/neuron; flag==0 -> done (zeros are exact);
//     else recompute the full row with the verified R10 event-driven
//     conv + scan and overwrite. Exact for ALL inputs.
// Fallback: ws too small -> single-kernel R10 path (kept verbatim).
//
// Bit-exactness invariant (absmax must stay 0.0): K1's u accumulates taps
// j=1..76 ascending in ONE fmaf chain (bands j=1..16,...,65..76), operands
// exactly the input floats (zeros for t<0) -- the same chain as every
// passing round; K2's fallback is R10's verified body. No reassociation.

#define T_LEN 300
#define CH 20
#define NCHUNK 15          // 15 * 20 == 300 exactly
#define KS 77              // srm kernel length (alpha, tau=10, eps_tol=0.01)
#define KR 10              // ref kernel tail length (K_ref=11 -> 10 pending)
#define THETA_V 10.0f
#define TSZ 115            // K2 gather table: idx = 95 + c - p

// ---------------- K1: banded dense conv + flag + zero-store ----------------
__global__ __launch_bounds__(256) void conv_flag_kernel(
    const float* __restrict__ spike_in,
    const float* __restrict__ srm, int srm_len,
    float* __restrict__ out, unsigned* __restrict__ flags, int B)
{
    const int b  = blockIdx.x * blockDim.x + threadIdx.x;   // neuron
    const int ch = blockIdx.y;                              // chunk (uniform)
    if (b >= B) return;

    const float* row = spike_in + (size_t)b * T_LEN;
    const int t0 = ch * CH;

    // srm taps (uniform-address loads -> scalarized). Tap 0 == 0.0, skipped.
    float srm_r[KS];
#pragma unroll
    for (int i = 1; i < KS; ++i) srm_r[i] = (i < srm_len) ? srm[i] : 0.0f;

    float u[CH];
#pragma unroll
    for (int c = 0; c < CH; ++c) u[c] = 0.0f;

    // bands 0..3: taps j = 16*bb+d, d=1..16; window x[t0-16(bb+1) .. t0+19].
    // Window byte offset (t0-16(bb+1))*4 = 80ch-64(bb+1)*... always 16B-
    // aligned (both terms mult of 16). f < 0 => f <= -4 => whole float4
    // is pre-time zeros (guard is ch-uniform -> scalar branch, no diverge).
#pragma unroll
    for (int bb = 0; bb < 4; ++bb) {
        const int wbase = t0 - 16 * (bb + 1);
        float xw[36];
#pragma unroll
        for (int i = 0; i < 9; ++i) {
            const int f = wbase + 4 * i;
            float4 v;
            if (f >= 0) v = *(const float4*)(row + f);
            else        v = make_float4(0.0f, 0.0f, 0.0f, 0.0f);
            xw[4*i+0] = v.x; xw[4*i+1] = v.y; xw[4*i+2] = v.z; xw[4*i+3] = v.w;
        }
#pragma unroll
        for (int d = 1; d <= 16; ++d) {
            const float w = srm_r[16 * bb + d];
#pragma unroll
            for (int c = 0; c < CH; ++c)
                u[c] = fmaf(w, xw[16 - d + c], u[c]);
        }
    }
    // band 4: taps j = 64+d, d=1..12; window x[t0-76 .. t0-45] (32 floats)
    {
        const int wbase = t0 - 76;
        float xw[32];
#pragma unroll
        for (int i = 0; i < 8; ++i) {
            const int f = wbase + 4 * i;
            float4 v;
            if (f >= 0) v = *(const float4*)(row + f);
            else        v = make_float4(0.0f, 0.0f, 0.0f, 0.0f);
            xw[4*i+0] = v.x; xw[4*i+1] = v.y; xw[4*i+2] = v.z; xw[4*i+3] = v.w;
        }
#pragma unroll
        for (int d = 1; d <= 12; ++d) {
            const float w = srm_r[64 + d];
#pragma unroll
            for (int c = 0; c < CH; ++c)
                u[c] = fmaf(w, xw[12 - d + c], u[c]);
        }
    }

    // u is bit-identical to the verified sequential chain. Theorem: spike
    // requires u >= theta (pend <= 0). Flag rows that might fire.
    bool any_ge = false;
#pragma unroll
    for (int c = 0; c < CH; ++c) any_ge = any_ge || (u[c] >= THETA_V);
    if (any_ge) atomicOr(&flags[b], 1u);

    // fast-path output: zeros (exact unless the row is flagged; flagged
    // rows are fully rewritten by the scan kernel).
    const float4 z = make_float4(0.0f, 0.0f, 0.0f, 0.0f);
    float4* op = (float4*)(out + (size_t)b * T_LEN + t0);
#pragma unroll
    for (int i = 0; i < CH / 4; ++i) op[i] = z;
}

// ------------- K2: flagged rows -> verified sequential recompute -----------
__global__ __launch_bounds__(256) void scan_fix_kernel(
    const float* __restrict__ spike_in,
    const float* __restrict__ srm, int srm_len,
    const float* __restrict__ refk, int ref_len,
    float* __restrict__ out, const unsigned* __restrict__ flags, int B)
{
    __shared__ float T[TSZ + 13];
    {
        int k = threadIdx.x;
        if (k < TSZ + 13) {
            int j = k - 19;
            T[k] = (j >= 1 && j < KS && j < srm_len) ? srm[j] : 0.0f;
        }
    }
    __syncthreads();

    int b = blockIdx.x * blockDim.x + threadIdx.x;
    if (b >= B) return;
    if (flags[b] == 0u) return;     // zeros already stored by K1: exact

    const float* row  = spike_in + (size_t)b * T_LEN;
    float*       orow = out      + (size_t)b * T_LEN;

    float rt[KR];
#pragma unroll
    for (int i = 0; i < KR; ++i) rt[i] = (i + 1 < ref_len) ? refk[i + 1] : 0.0f;
    float pend[KR];
#pragma unroll
    for (int i = 0; i < KR; ++i) pend[i] = 0.0f;

    unsigned w0 = 0, w1 = 0, w2 = 0;
    float nxt[CH];
    {
        const float4* p = (const float4*)row;
#pragma unroll
        for (int i = 0; i < CH / 4; ++i) {
            float4 v = p[i];
            nxt[4*i+0] = v.x; nxt[4*i+1] = v.y; nxt[4*i+2] = v.z; nxt[4*i+3] = v.w;
        }
    }

#pragma unroll 1
    for (int ch = 0; ch < NCHUNK; ++ch) {
        unsigned nb = 0;
#pragma unroll
        for (int i = 0; i < CH; ++i)
            nb |= (nxt[i] != 0.0f) ? (1u << i) : 0u;

        w0 = (w0 >> 20) | (w1 << 12);
        w1 = (w1 >> 20) | (w2 << 12);
        w2 = (w2 >> 20) | (nb << 12);

        if (ch + 1 < NCHUNK) {
            const float4* p = (const float4*)(row + (ch + 1) * CH);
#pragma unroll
            for (int i = 0; i < CH / 4; ++i) {
                float4 v = p[i];
                nxt[4*i+0] = v.x; nxt[4*i+1] = v.y; nxt[4*i+2] = v.z; nxt[4*i+3] = v.w;
            }
        }
        __builtin_amdgcn_sched_barrier(0);

        float u[CH];
#pragma unroll
        for (int c = 0; c < CH; ++c) u[c] = 0.0f;

        unsigned a0 = w0, a1 = w1, a2 = w2;
        while (__ballot(a0 | a1 | a2)) {
            int p = a2 ? (95 - __clz(a2))
                       : (a1 ? (63 - __clz(a1))
                             : (a0 ? (31 - __clz(a0)) : 95));
            unsigned m = 1u << (p & 31);
            if (p >= 64)      a2 &= ~m;
            else if (p >= 32) a1 &= ~m;
            else              a0 &= ~m;

            const float* tp = &T[95 - p];
#pragma unroll
            for (int c = 0; c < CH; ++c)
                u[c] += tp[c];          // == fmaf(srm[j], 1.0f, u[c])
        }

        float so[CH];
#pragma unroll
        for (int c = 0; c < CH; ++c) {
            const int r = c % KR;
            float u_eff = u[c] + pend[r];
            float s = (u_eff >= THETA_V) ? 1.0f : 0.0f;
#pragma unroll
            for (int i = 0; i < KR - 1; ++i)
                pend[(r + 1 + i) % KR] = fmaf(s, rt[i], pend[(r + 1 + i) % KR]);
            pend[r] = s * rt[KR - 1];
            so[c] = s;
        }

        float4* op = (float4*)(orow + ch * CH);
#pragma unroll
        for (int i = 0; i < CH / 4; ++i) {
            float4 v;
            v.x = so[4*i+0]; v.y = so[4*i+1]; v.z = so[4*i+2]; v.w = so[4*i+3];
            op[i] = v;
        }
    }
}

// --------- fallback: round-10 single-kernel path (ws too small) ------------
__global__ __launch_bounds__(256)
__attribute__((amdgpu_waves_per_eu(1, 1)))
void spike_layer_kernel(
    const float* __restrict__ spike_in,
    const float* __restrict__ srm, int srm_len,
    const float* __restrict__ refk, int ref_len,
    float* __restrict__ out, int B)
{
    __shared__ float T[TSZ + 13];
    {
        int k = threadIdx.x;
        if (k < TSZ + 13) {
            int j = k - 19;
            T[k] = (j >= 1 && j < KS && j < srm_len) ? srm[j] : 0.0f;
        }
    }
    __syncthreads();

    int b = blockIdx.x * blockDim.x + threadIdx.x;
    if (b >= B) return;

    const float* row  = spike_in + (size_t)b * T_LEN;
    float*       orow = out      + (size_t)b * T_LEN;

    float rt[KR];
#pragma unroll
    for (int i = 0; i < KR; ++i) rt[i] = (i + 1 < ref_len) ? refk[i + 1] : 0.0f;
    float pend[KR];
#pragma unroll
    for (int i = 0; i < KR; ++i) pend[i] = 0.0f;

    unsigned w0 = 0, w1 = 0, w2 = 0;
    float nxt[CH];
    {
        const float4* p = (const float4*)row;
#pragma unroll
        for (int i = 0; i < CH / 4; ++i) {
            float4 v = p[i];
            nxt[4*i+0] = v.x; nxt[4*i+1] = v.y; nxt[4*i+2] = v.z; nxt[4*i+3] = v.w;
        }
    }

#pragma unroll 1
    for (int ch = 0; ch < NCHUNK; ++ch) {
        unsigned nb = 0;
#pragma unroll
        for (int i = 0; i < CH; ++i)
            nb |= (nxt[i] != 0.0f) ? (1u << i) : 0u;

        w0 = (w0 >> 20) | (w1 << 12);
        w1 = (w1 >> 20) | (w2 << 12);
        w2 = (w2 >> 20) | (nb << 12);

        if (ch + 1 < NCHUNK) {
            const float4* p = (const float4*)(row + (ch + 1) * CH);
#pragma unroll
            for (int i = 0; i < CH / 4; ++i) {
                float4 v = p[i];
                nxt[4*i+0] = v.x; nxt[4*i+1] = v.y; nxt[4*i+2] = v.z; nxt[4*i+3] = v.w;
            }
        }
        __builtin_amdgcn_sched_barrier(0);

        float u[CH];
#pragma unroll
        for (int c = 0; c < CH; ++c) u[c] = 0.0f;

        unsigned a0 = w0, a1 = w1, a2 = w2;
        while (__ballot(a0 | a1 | a2)) {
            int p = a2 ? (95 - __clz(a2))
                       : (a1 ? (63 - __clz(a1))
                             : (a0 ? (31 - __clz(a0)) : 95));
            unsigned m = 1u << (p & 31);
            if (p >= 64)      a2 &= ~m;
            else if (p >= 32) a1 &= ~m;
            else              a0 &= ~m;

            const float* tp = &T[95 - p];
#pragma unroll
            for (int c = 0; c < CH; ++c)
                u[c] += tp[c];
        }

        float so[CH];
#pragma unroll
        for (int c = 0; c < CH; ++c) {
            const int r = c % KR;
            float u_eff = u[c] + pend[r];
            float s = (u_eff >= THETA_V) ? 1.0f : 0.0f;
#pragma unroll
            for (int i = 0; i < KR - 1; ++i)
                pend[(r + 1 + i) % KR] = fmaf(s, rt[i], pend[(r + 1 + i) % KR]);
            pend[r] = s * rt[KR - 1];
            so[c] = s;
        }

        float4* op = (float4*)(orow + ch * CH);
#pragma unroll
        for (int i = 0; i < CH / 4; ++i) {
            float4 v;
            v.x = so[4*i+0]; v.y = so[4*i+1]; v.z = so[4*i+2]; v.w = so[4*i+3];
            op[i] = v;
        }
    }
}

extern "C" void kernel_launch(void* const* d_in, const int* in_sizes, int n_in,
                              void* d_out, int out_size, void* d_ws, size_t ws_size,
                              hipStream_t stream) {
    const float* spike_in = (const float*)d_in[0];
    const float* srm      = (const float*)d_in[1];
    const float* refk     = (const float*)d_in[2];
    float* out = (float*)d_out;

    int srm_len = in_sizes[1];
    int ref_len = in_sizes[2];
    int B = in_sizes[0] / T_LEN;   // 65536 neurons

    if (d_ws != nullptr && ws_size >= (size_t)B * sizeof(unsigned)) {
        unsigned* flags = (unsigned*)d_ws;
        hipMemsetAsync(flags, 0, (size_t)B * sizeof(unsigned), stream);
        dim3 grid1((B + 255) / 256, NCHUNK, 1);
        conv_flag_kernel<<<grid1, 256, 0, stream>>>(spike_in, srm, srm_len,
                                                    out, flags, B);
        scan_fix_kernel<<<(B + 255) / 256, 256, 0, stream>>>(
            spike_in, srm, srm_len, refk, ref_len, out, flags, B);
    } else {
        int grid = (B + 255) / 256;
        spike_layer_kernel<<<grid, 256, 0, stream>>>(spike_in, srm, srm_len,
                                                     refk, ref_len, out, B);
    }
}

// Round 12
// 242.956 us; speedup vs baseline: 1.3746x; 1.3746x over previous
//
#include <hip/hip_runtime.h>

// SNN spike layer: causal alpha-PSP FIR conv (taps 1..76; srm[0]==0 exactly)
// + sequential refractory threshold scan.
//
// Round-12: K1 = R10's event-driven conv (small live set, few insts) x
// R11's chunk-parallel decoupled structure (15 waves/SIMD of TLP).
// Theorem (exact, all inputs): ref tail rt[] <= 0 => pend <= 0 =>
// u_eff = u + pend <= u; if u[t] < theta for all t of a row, no spike
// fires. K1 computes u per (neuron, chunk) bit-identically to the verified
// sequential chain, flags rows with any u >= theta, stores zeros. K2
// rewrites flagged rows with the verified R10 conv+scan. For all-zero-
// output inputs (this bench: max u ~6.5 << 10) K2 is a no-op pass.
// R11 K1 failure fixed: dense conv needed ~135 live regs (VGPR 136,
// spills, WRITE +20MB, 17.8% VALU). Event-driven K1 live set ~70 regs:
// 96-bit window (3 VGPRs) + u[20] + pack staging. No spill trigger.
//
// Bit-exactness invariant (absmax must stay 0.0): operands exactly 0/1;
// descending-MSB spike processing = ascending-j term order (the chain
// verified in every passing round); zero-padded T gives exact +0 for
// j outside [1,76]; u + T == fmaf(T,1,u); scan step identical. No
// reassociation anywhere.

#define T_LEN 300
#define CH 20
#define NCHUNK 15          // 15 * 20 == 300 exactly
#define KS 77              // srm kernel length (alpha, tau=10, eps_tol=0.01)
#define KR 10              // ref kernel tail length (K_ref=11 -> 10 pending)
#define THETA_V 10.0f
#define TSZ 115            // T table: idx = 95 + c - p, p in [0,95], c in [0,19]

// ---------------- K1: event-driven conv + flag + zero-store ----------------
__global__ __launch_bounds__(256) void conv_flag_kernel(
    const float* __restrict__ spike_in,
    const float* __restrict__ srm, int srm_len,
    float* __restrict__ out, unsigned* __restrict__ flags, int B)
{
    // zero-padded srm gather table: T[k] = srm[k-19] iff 1 <= k-19 <= 76
    __shared__ float T[TSZ + 13];   // 128 floats
    {
        int k = threadIdx.x;
        if (k < TSZ + 13) {
            int j = k - 19;
            T[k] = (j >= 1 && j < KS && j < srm_len) ? srm[j] : 0.0f;
        }
    }
    __syncthreads();                 // before any early return

    const int b  = blockIdx.x * blockDim.x + threadIdx.x;   // neuron
    const int ch = blockIdx.y;                              // chunk (uniform)
    if (b >= B) return;

    const float* row = spike_in + (size_t)b * T_LEN;
    const int t0    = ch * CH;
    const int wbase = t0 - 76;       // float index of window bit 0 (mult of 4)

    // pack 96-bit window: bit k = (x[wbase+k] != 0), t<0 -> 0.
    // Guards are ch-uniform (scalar branch, no divergence); addresses
    // 16B-aligned (wbase and 32g+4i both multiples of 4 floats).
    unsigned w0 = 0, w1 = 0, w2 = 0;
#pragma unroll
    for (int g = 0; g < 3; ++g) {
        unsigned wg = 0;
#pragma unroll
        for (int i = 0; i < 8; ++i) {
            const int f = wbase + 32 * g + 4 * i;
            if (f >= 0) {
                float4 v = *(const float4*)(row + f);
                wg |= (v.x != 0.0f ? 1u : 0u) << (4 * i + 0);
                wg |= (v.y != 0.0f ? 1u : 0u) << (4 * i + 1);
                wg |= (v.z != 0.0f ? 1u : 0u) << (4 * i + 2);
                wg |= (v.w != 0.0f ? 1u : 0u) << (4 * i + 3);
            }
        }
        if (g == 0) w0 = wg; else if (g == 1) w1 = wg; else w2 = wg;
    }

    // ---- event-driven conv over set bits, DESCENDING p (verified body) ----
    float u[CH];
#pragma unroll
    for (int c = 0; c < CH; ++c) u[c] = 0.0f;

    unsigned a0 = w0, a1 = w1, a2 = w2;
    while (__ballot(a0 | a1 | a2)) {
        // per-lane MSB of the 96-bit residual; 95 (neutral: exact zeros
        // from T) if this lane is already empty.
        int p = a2 ? (95 - __clz(a2))
                   : (a1 ? (63 - __clz(a1))
                         : (a0 ? (31 - __clz(a0)) : 95));
        unsigned m = 1u << (p & 31);
        if (p >= 64)      a2 &= ~m;
        else if (p >= 32) a1 &= ~m;
        else              a0 &= ~m;

        const float* tp = &T[95 - p];
#pragma unroll
        for (int c = 0; c < CH; ++c)
            u[c] += tp[c];           // == fmaf(srm[j], 1.0f, u[c])
    }

    // u is bit-identical to the sequential chain's u. Theorem: firing
    // requires u_eff = u + pend >= theta and pend <= 0, so u >= theta is
    // necessary. Flag rows that might fire anywhere in this chunk.
    bool any_ge = false;
#pragma unroll
    for (int c = 0; c < CH; ++c) any_ge = any_ge || (u[c] >= THETA_V);
    if (any_ge) atomicOr(&flags[b], 1u);

    // fast-path output: zeros (exact unless flagged; flagged rows are
    // fully rewritten by K2).
    const float4 z = make_float4(0.0f, 0.0f, 0.0f, 0.0f);
    float4* op = (float4*)(out + (size_t)b * T_LEN + t0);
#pragma unroll
    for (int i = 0; i < CH / 4; ++i) op[i] = z;
}

// ------------- K2: flagged rows -> verified sequential recompute -----------
__global__ __launch_bounds__(256) void scan_fix_kernel(
    const float* __restrict__ spike_in,
    const float* __restrict__ srm, int srm_len,
    const float* __restrict__ refk, int ref_len,
    float* __restrict__ out, const unsigned* __restrict__ flags, int B)
{
    __shared__ float T[TSZ + 13];
    {
        int k = threadIdx.x;
        if (k < TSZ + 13) {
            int j = k - 19;
            T[k] = (j >= 1 && j < KS && j < srm_len) ? srm[j] : 0.0f;
        }
    }
    __syncthreads();

    int b = blockIdx.x * blockDim.x + threadIdx.x;
    if (b >= B) return;
    if (flags[b] == 0u) return;     // zeros already stored by K1: exact

    const float* row  = spike_in + (size_t)b * T_LEN;
    float*       orow = out      + (size_t)b * T_LEN;

    float rt[KR];
#pragma unroll
    for (int i = 0; i < KR; ++i) rt[i] = (i + 1 < ref_len) ? refk[i + 1] : 0.0f;
    float pend[KR];
#pragma unroll
    for (int i = 0; i < KR; ++i) pend[i] = 0.0f;

    unsigned w0 = 0, w1 = 0, w2 = 0;
    float nxt[CH];
    {
        const float4* p = (const float4*)row;
#pragma unroll
        for (int i = 0; i < CH / 4; ++i) {
            float4 v = p[i];
            nxt[4*i+0] = v.x; nxt[4*i+1] = v.y; nxt[4*i+2] = v.z; nxt[4*i+3] = v.w;
        }
    }

#pragma unroll 1
    for (int ch = 0; ch < NCHUNK; ++ch) {
        unsigned nb = 0;
#pragma unroll
        for (int i = 0; i < CH; ++i)
            nb |= (nxt[i] != 0.0f) ? (1u << i) : 0u;

        w0 = (w0 >> 20) | (w1 << 12);
        w1 = (w1 >> 20) | (w2 << 12);
        w2 = (w2 >> 20) | (nb << 12);

        if (ch + 1 < NCHUNK) {
            const float4* p = (const float4*)(row + (ch + 1) * CH);
#pragma unroll
            for (int i = 0; i < CH / 4; ++i) {
                float4 v = p[i];
                nxt[4*i+0] = v.x; nxt[4*i+1] = v.y; nxt[4*i+2] = v.z; nxt[4*i+3] = v.w;
            }
        }
        __builtin_amdgcn_sched_barrier(0);

        float u[CH];
#pragma unroll
        for (int c = 0; c < CH; ++c) u[c] = 0.0f;

        unsigned a0 = w0, a1 = w1, a2 = w2;
        while (__ballot(a0 | a1 | a2)) {
            int p = a2 ? (95 - __clz(a2))
                       : (a1 ? (63 - __clz(a1))
                             : (a0 ? (31 - __clz(a0)) : 95));
            unsigned m = 1u << (p & 31);
            if (p >= 64)      a2 &= ~m;
            else if (p >= 32) a1 &= ~m;
            else              a0 &= ~m;

            const float* tp = &T[95 - p];
#pragma unroll
            for (int c = 0; c < CH; ++c)
                u[c] += tp[c];
        }

        float so[CH];
#pragma unroll
        for (int c = 0; c < CH; ++c) {
            const int r = c % KR;
            float u_eff = u[c] + pend[r];
            float s = (u_eff >= THETA_V) ? 1.0f : 0.0f;
#pragma unroll
            for (int i = 0; i < KR - 1; ++i)
                pend[(r + 1 + i) % KR] = fmaf(s, rt[i], pend[(r + 1 + i) % KR]);
            pend[r] = s * rt[KR - 1];
            so[c] = s;
        }

        float4* op = (float4*)(orow + ch * CH);
#pragma unroll
        for (int i = 0; i < CH / 4; ++i) {
            float4 v;
            v.x = so[4*i+0]; v.y = so[4*i+1]; v.z = so[4*i+2]; v.w = so[4*i+3];
            op[i] = v;
        }
    }
}

// --------- fallback: round-10 single-kernel path (ws too small) ------------
__global__ __launch_bounds__(256)
__attribute__((amdgpu_waves_per_eu(1, 1)))
void spike_layer_kernel(
    const float* __restrict__ spike_in,
    const float* __restrict__ srm, int srm_len,
    const float* __restrict__ refk, int ref_len,
    float* __restrict__ out, int B)
{
    __shared__ float T[TSZ + 13];
    {
        int k = threadIdx.x;
        if (k < TSZ + 13) {
            int j = k - 19;
            T[k] = (j >= 1 && j < KS && j < srm_len) ? srm[j] : 0.0f;
        }
    }
    __syncthreads();

    int b = blockIdx.x * blockDim.x + threadIdx.x;
    if (b >= B) return;

    const float* row  = spike_in + (size_t)b * T_LEN;
    float*       orow = out      + (size_t)b * T_LEN;

    float rt[KR];
#pragma unroll
    for (int i = 0; i < KR; ++i) rt[i] = (i + 1 < ref_len) ? refk[i + 1] : 0.0f;
    float pend[KR];
#pragma unroll
    for (int i = 0; i < KR; ++i) pend[i] = 0.0f;

    unsigned w0 = 0, w1 = 0, w2 = 0;
    float nxt[CH];
    {
        const float4* p = (const float4*)row;
#pragma unroll
        for (int i = 0; i < CH / 4; ++i) {
            float4 v = p[i];
            nxt[4*i+0] = v.x; nxt[4*i+1] = v.y; nxt[4*i+2] = v.z; nxt[4*i+3] = v.w;
        }
    }

#pragma unroll 1
    for (int ch = 0; ch < NCHUNK; ++ch) {
        unsigned nb = 0;
#pragma unroll
        for (int i = 0; i < CH; ++i)
            nb |= (nxt[i] != 0.0f) ? (1u << i) : 0u;

        w0 = (w0 >> 20) | (w1 << 12);
        w1 = (w1 >> 20) | (w2 << 12);
        w2 = (w2 >> 20) | (nb << 12);

        if (ch + 1 < NCHUNK) {
            const float4* p = (const float4*)(row + (ch + 1) * CH);
#pragma unroll
            for (int i = 0; i < CH / 4; ++i) {
                float4 v = p[i];
                nxt[4*i+0] = v.x; nxt[4*i+1] = v.y; nxt[4*i+2] = v.z; nxt[4*i+3] = v.w;
            }
        }
        __builtin_amdgcn_sched_barrier(0);

        float u[CH];
#pragma unroll
        for (int c = 0; c < CH; ++c) u[c] = 0.0f;

        unsigned a0 = w0, a1 = w1, a2 = w2;
        while (__ballot(a0 | a1 | a2)) {
            int p = a2 ? (95 - __clz(a2))
                       : (a1 ? (63 - __clz(a1))
                             : (a0 ? (31 - __clz(a0)) : 95));
            unsigned m = 1u << (p & 31);
            if (p >= 64)      a2 &= ~m;
            else if (p >= 32) a1 &= ~m;
            else              a0 &= ~m;

            const float* tp = &T[95 - p];
#pragma unroll
            for (int c = 0; c < CH; ++c)
                u[c] += tp[c];
        }

        float so[CH];
#pragma unroll
        for (int c = 0; c < CH; ++c) {
            const int r = c % KR;
            float u_eff = u[c] + pend[r];
            float s = (u_eff >= THETA_V) ? 1.0f : 0.0f;
#pragma unroll
            for (int i = 0; i < KR - 1; ++i)
                pend[(r + 1 + i) % KR] = fmaf(s, rt[i], pend[(r + 1 + i) % KR]);
            pend[r] = s * rt[KR - 1];
            so[c] = s;
        }

        float4* op = (float4*)(orow + ch * CH);
#pragma unroll
        for (int i = 0; i < CH / 4; ++i) {
            float4 v;
            v.x = so[4*i+0]; v.y = so[4*i+1]; v.z = so[4*i+2]; v.w = so[4*i+3];
            op[i] = v;
        }
    }
}

extern "C" void kernel_launch(void* const* d_in, const int* in_sizes, int n_in,
                              void* d_out, int out_size, void* d_ws, size_t ws_size,
                              hipStream_t stream) {
    const float* spike_in = (const float*)d_in[0];
    const float* srm      = (const float*)d_in[1];
    const float* refk     = (const float*)d_in[2];
    float* out = (float*)d_out;

    int srm_len = in_sizes[1];
    int ref_len = in_sizes[2];
    int B = in_sizes[0] / T_LEN;   // 65536 neurons

    if (d_ws != nullptr && ws_size >= (size_t)B * sizeof(unsigned)) {
        unsigned* flags = (unsigned*)d_ws;
        hipMemsetAsync(flags, 0, (size_t)B * sizeof(unsigned), stream);
        dim3 grid1((B + 255) / 256, NCHUNK, 1);
        conv_flag_kernel<<<grid1, 256, 0, stream>>>(spike_in, srm, srm_len,
                                                    out, flags, B);
        scan_fix_kernel<<<(B + 255) / 256, 256, 0, stream>>>(
            spike_in, srm, srm_len, refk, ref_len, out, flags, B);
    } else {
        int grid = (B + 255) / 256;
        spike_layer_kernel<<<grid, 256, 0, stream>>>(spike_in, srm, srm_len,
                                                     refk, ref_len, out, B);
    }
}

// Round 13
// 191.353 us; speedup vs baseline: 1.7453x; 1.2697x over previous
//
#include <hip/hip_runtime.h>

// SNN spike layer: causal alpha-PSP FIR conv (taps 1..76; srm[0]==0 exactly)
// + sequential refractory threshold scan.
//
// Round-13: BIT-PACKED 3-dispatch pipeline. 12-round ledger: the row-major
// [neuron][time] layout with thread=neuron scatters every access (stride
// 1200B); chunk-splitting (R12) fixed TLP but multiplied the scatter
// (VALU 14%, 148us). Fix: shrink the operand 32x first.
//   K0 pack: coalesced dword loads + __ballot -> flat bit array (bit i =
//     spike_in[i] != 0; 4 guard words of zeros in front). 2.5 MB, L2-fits.
//     Also zeros the flags.
//   K1 conv+flag+zero: thread=(neuron,chunk), tid=n*15+ch -> 983k threads,
//     15 waves/SIMD. Window = 4 u32 loads + 64-bit funnel shifts + prev-row
//     mask. Dense-from-bits conv (bfe+cvt operand regen, ascending-j fmaf
//     chain, live set ~75 regs -> below the allocator's 96 target, no LDS,
//     no divergence). Theorem (exact, all inputs): ref tail rt[] <= 0 =>
//     pend <= 0 => u_eff <= u; firing requires u >= theta, so unflagged
//     rows are provably all-zero. Zero-stores perfectly coalesced (lane i
//     writes bytes [80i,80i+80) of consecutive rows = 5120 contiguous
//     B/wave). atomicOr(flags) on any u >= theta.
//   K2 fix-up: flagged rows -> verified R10 event-driven conv + sequential
//     scan (unchanged, 3rd time deployed).
// Fallback (ws < ~2.75 MB): verified R10 single-kernel (82us).
// Bench fixed overhead ~95us is dispatch-count-independent (R0/R10/R12).
//
// Bit-exactness invariant (absmax must stay 0.0): operands exactly 0/1;
// (float)((w>>p)&1) reproduces them exactly; each u[t] accumulates taps
// j=1..76 ascending in ONE fmaf chain (bands j=1..16,...,65..76); K2 scan
// identical to every verified round. No reassociation anywhere.

#define T_LEN 300
#define CH 20
#define NCHUNK 15          // 15 * 20 == 300 exactly
#define KS 77              // srm kernel length (alpha, tau=10, eps_tol=0.01)
#define KR 10              // ref kernel tail length (K_ref=11 -> 10 pending)
#define THETA_V 10.0f
#define TSZ 115            // K2 gather table: idx = 95 + c - p

// ---------------- K0: bit-pack input (coalesced) + zero flags ----------------
__global__ __launch_bounds__(256) void pack_kernel(
    const float* __restrict__ spike_in, unsigned* __restrict__ packed,
    unsigned* __restrict__ flags, long long N, long long ngroups, int B)
{
    const int lane = threadIdx.x & 63;
    const long long wid = (long long)blockIdx.x * (blockDim.x >> 6) + (threadIdx.x >> 6);
    const long long nw  = (long long)gridDim.x * (blockDim.x >> 6);
    const long long gtid = (long long)blockIdx.x * blockDim.x + threadIdx.x;
    const long long nthr = (long long)gridDim.x * blockDim.x;

    if (gtid < 4) packed[gtid] = 0u;              // guard words: bits -128..-1
    for (long long i = gtid; i < B; i += nthr) flags[i] = 0u;

    // wave handles 64 consecutive floats per group: lane load fully coalesced
    for (long long g = wid; g < ngroups; g += nw) {
        const long long f = g * 64 + lane;
        float x = (f < N) ? spike_in[f] : 0.0f;
        unsigned long long m = __ballot(x != 0.0f);   // bit L = lane L pred
        if (lane == 0) packed[4 + 2 * g]     = (unsigned)m;
        if (lane == 1) packed[4 + 2 * g + 1] = (unsigned)(m >> 32);
    }
}

// -------- K1: dense-from-bits conv + flag + coalesced zero-store -----------
__global__ __launch_bounds__(256) void conv_flag_kernel(
    const unsigned* __restrict__ packed,
    const float* __restrict__ srm, int srm_len,
    float* __restrict__ out, unsigned* __restrict__ flags, int B)
{
    const int tid = blockIdx.x * blockDim.x + threadIdx.x;
    if (tid >= B * NCHUNK) return;
    const int n  = tid / NCHUNK;                  // magic-mul div
    const int ch = tid - n * NCHUNK;

    // srm taps (uniform-address loads -> scalarized to SGPRs). Tap 0 == 0.
    float srm_r[KS];
#pragma unroll
    for (int i = 1; i < KS; ++i) srm_r[i] = (i < srm_len) ? srm[i] : 0.0f;

    // window bit k (k=0..95) = flat input bit F0+k, F0 = 300n + 20ch - 76.
    // packed array has a 128-bit zero guard in front: G = F0 + 128 >= 52.
    const long long G = 300LL * n + 20 * ch - 76 + 128;
    const int q = (int)(G >> 5);
    const int r = (int)(G & 31);
    const unsigned W0 = packed[q],     W1 = packed[q + 1];
    const unsigned W2 = packed[q + 2], W3 = packed[q + 3];
    unsigned w0 = (unsigned)((((unsigned long long)W1 << 32) | W0) >> r);
    unsigned w1 = (unsigned)((((unsigned long long)W2 << 32) | W1) >> r);
    unsigned w2 = (unsigned)((((unsigned long long)W3 << 32) | W2) >> r);

    // clear window bits belonging to t<0 / the PREVIOUS row: k < 76-20ch.
    if (ch < 4) {
        const int nz = 76 - 20 * ch;              // 76,56,36,16
        if (nz >= 64)      { w0 = 0u; w1 = 0u; w2 &= ~((1u << (nz - 64)) - 1u); }
        else if (nz >= 32) { w0 = 0u; w1 &= ~((1u << (nz - 32)) - 1u); }
        else               { w0 &= ~((1u << nz) - 1u); }
    }

    // conv: u[c] = sum_{j=1..76} srm[j] * bit(76+c-j); ascending-j fmaf chain
    float u[CH];
#pragma unroll
    for (int c = 0; c < CH; ++c) u[c] = 0.0f;

    // bands 0..3: taps j = 16*bb+d, d=1..16; window bits [60-16bb, 94-16bb]
#pragma unroll
    for (int bb = 0; bb < 4; ++bb) {
        const int base = 60 - 16 * bb;
        float xw[35];                              // xw[m] = bit(base+m)
#pragma unroll
        for (int m = 0; m < 35; ++m) {
            const int p = base + m;                // compile-time
            const unsigned reg = (p < 32) ? w0 : ((p < 64) ? w1 : w2);
            xw[m] = (float)((reg >> (p & 31)) & 1u);   // v_bfe + v_cvt
        }
#pragma unroll
        for (int d = 1; d <= 16; ++d) {
            const float wt = srm_r[16 * bb + d];
#pragma unroll
            for (int c = 0; c < CH; ++c)
                u[c] = fmaf(wt, xw[16 - d + c], u[c]);
        }
    }
    // band 4: taps j = 64+d, d=1..12; window bits 0..30 (all in w0)
    {
        float xw[31];
#pragma unroll
        for (int m = 0; m < 31; ++m)
            xw[m] = (float)((w0 >> m) & 1u);
#pragma unroll
        for (int d = 1; d <= 12; ++d) {
            const float wt = srm_r[64 + d];
#pragma unroll
            for (int c = 0; c < CH; ++c)
                u[c] = fmaf(wt, xw[12 - d + c], u[c]);
        }
    }

    // theorem: firing needs u_eff = u + pend >= theta and pend <= 0.
    bool any_ge = false;
#pragma unroll
    for (int c = 0; c < CH; ++c) any_ge = any_ge || (u[c] >= THETA_V);
    if (any_ge) atomicOr(&flags[n], 1u);

    // coalesced zero-store: tid=n*15+ch => wave writes 5120 contiguous bytes
    const float4 z = make_float4(0.0f, 0.0f, 0.0f, 0.0f);
    float4* op = (float4*)(out + (size_t)n * T_LEN + ch * CH);
#pragma unroll
    for (int i = 0; i < CH / 4; ++i) op[i] = z;
}

// ------------- K2: flagged rows -> verified sequential recompute -----------
__global__ __launch_bounds__(256) void scan_fix_kernel(
    const float* __restrict__ spike_in,
    const float* __restrict__ srm, int srm_len,
    const float* __restrict__ refk, int ref_len,
    float* __restrict__ out, const unsigned* __restrict__ flags, int B)
{
    __shared__ float T[TSZ + 13];
    {
        int k = threadIdx.x;
        if (k < TSZ + 13) {
            int j = k - 19;
            T[k] = (j >= 1 && j < KS && j < srm_len) ? srm[j] : 0.0f;
        }
    }
    __syncthreads();

    int b = blockIdx.x * blockDim.x + threadIdx.x;
    if (b >= B) return;
    if (flags[b] == 0u) return;     // zeros already stored by K1: exact

    const float* row  = spike_in + (size_t)b * T_LEN;
    float*       orow = out      + (size_t)b * T_LEN;

    float rt[KR];
#pragma unroll
    for (int i = 0; i < KR; ++i) rt[i] = (i + 1 < ref_len) ? refk[i + 1] : 0.0f;
    float pend[KR];
#pragma unroll
    for (int i = 0; i < KR; ++i) pend[i] = 0.0f;

    unsigned w0 = 0, w1 = 0, w2 = 0;
    float nxt[CH];
    {
        const float4* p = (const float4*)row;
#pragma unroll
        for (int i = 0; i < CH / 4; ++i) {
            float4 v = p[i];
            nxt[4*i+0] = v.x; nxt[4*i+1] = v.y; nxt[4*i+2] = v.z; nxt[4*i+3] = v.w;
        }
    }

#pragma unroll 1
    for (int ch = 0; ch < NCHUNK; ++ch) {
        unsigned nb = 0;
#pragma unroll
        for (int i = 0; i < CH; ++i)
            nb |= (nxt[i] != 0.0f) ? (1u << i) : 0u;

        w0 = (w0 >> 20) | (w1 << 12);
        w1 = (w1 >> 20) | (w2 << 12);
        w2 = (w2 >> 20) | (nb << 12);

        if (ch + 1 < NCHUNK) {
            const float4* p = (const float4*)(row + (ch + 1) * CH);
#pragma unroll
            for (int i = 0; i < CH / 4; ++i) {
                float4 v = p[i];
                nxt[4*i+0] = v.x; nxt[4*i+1] = v.y; nxt[4*i+2] = v.z; nxt[4*i+3] = v.w;
            }
        }
        __builtin_amdgcn_sched_barrier(0);

        float u[CH];
#pragma unroll
        for (int c = 0; c < CH; ++c) u[c] = 0.0f;

        unsigned a0 = w0, a1 = w1, a2 = w2;
        while (__ballot(a0 | a1 | a2)) {
            int p = a2 ? (95 - __clz(a2))
                       : (a1 ? (63 - __clz(a1))
                             : (a0 ? (31 - __clz(a0)) : 95));
            unsigned m = 1u << (p & 31);
            if (p >= 64)      a2 &= ~m;
            else if (p >= 32) a1 &= ~m;
            else              a0 &= ~m;

            const float* tp = &T[95 - p];
#pragma unroll
            for (int c = 0; c < CH; ++c)
                u[c] += tp[c];          // == fmaf(srm[j], 1.0f, u[c])
        }

        float so[CH];
#pragma unroll
        for (int c = 0; c < CH; ++c) {
            const int r = c % KR;
            float u_eff = u[c] + pend[r];
            float s = (u_eff >= THETA_V) ? 1.0f : 0.0f;
#pragma unroll
            for (int i = 0; i < KR - 1; ++i)
                pend[(r + 1 + i) % KR] = fmaf(s, rt[i], pend[(r + 1 + i) % KR]);
            pend[r] = s * rt[KR - 1];
            so[c] = s;
        }

        float4* op = (float4*)(orow + ch * CH);
#pragma unroll
        for (int i = 0; i < CH / 4; ++i) {
            float4 v;
            v.x = so[4*i+0]; v.y = so[4*i+1]; v.z = so[4*i+2]; v.w = so[4*i+3];
            op[i] = v;
        }
    }
}

// --------- fallback: round-10 single-kernel path (ws too small) ------------
__global__ __launch_bounds__(256)
__attribute__((amdgpu_waves_per_eu(1, 1)))
void spike_layer_kernel(
    const float* __restrict__ spike_in,
    const float* __restrict__ srm, int srm_len,
    const float* __restrict__ refk, int ref_len,
    float* __restrict__ out, int B)
{
    __shared__ float T[TSZ + 13];
    {
        int k = threadIdx.x;
        if (k < TSZ + 13) {
            int j = k - 19;
            T[k] = (j >= 1 && j < KS && j < srm_len) ? srm[j] : 0.0f;
        }
    }
    __syncthreads();

    int b = blockIdx.x * blockDim.x + threadIdx.x;
    if (b >= B) return;

    const float* row  = spike_in + (size_t)b * T_LEN;
    float*       orow = out      + (size_t)b * T_LEN;

    float rt[KR];
#pragma unroll
    for (int i = 0; i < KR; ++i) rt[i] = (i + 1 < ref_len) ? refk[i + 1] : 0.0f;
    float pend[KR];
#pragma unroll
    for (int i = 0; i < KR; ++i) pend[i] = 0.0f;

    unsigned w0 = 0, w1 = 0, w2 = 0;
    float nxt[CH];
    {
        const float4* p = (const float4*)row;
#pragma unroll
        for (int i = 0; i < CH / 4; ++i) {
            float4 v = p[i];
            nxt[4*i+0] = v.x; nxt[4*i+1] = v.y; nxt[4*i+2] = v.z; nxt[4*i+3] = v.w;
        }
    }

#pragma unroll 1
    for (int ch = 0; ch < NCHUNK; ++ch) {
        unsigned nb = 0;
#pragma unroll
        for (int i = 0; i < CH; ++i)
            nb |= (nxt[i] != 0.0f) ? (1u << i) : 0u;

        w0 = (w0 >> 20) | (w1 << 12);
        w1 = (w1 >> 20) | (w2 << 12);
        w2 = (w2 >> 20) | (nb << 12);

        if (ch + 1 < NCHUNK) {
            const float4* p = (const float4*)(row + (ch + 1) * CH);
#pragma unroll
            for (int i = 0; i < CH / 4; ++i) {
                float4 v = p[i];
                nxt[4*i+0] = v.x; nxt[4*i+1] = v.y; nxt[4*i+2] = v.z; nxt[4*i+3] = v.w;
            }
        }
        __builtin_amdgcn_sched_barrier(0);

        float u[CH];
#pragma unroll
        for (int c = 0; c < CH; ++c) u[c] = 0.0f;

        unsigned a0 = w0, a1 = w1, a2 = w2;
        while (__ballot(a0 | a1 | a2)) {
            int p = a2 ? (95 - __clz(a2))
                       : (a1 ? (63 - __clz(a1))
                             : (a0 ? (31 - __clz(a0)) : 95));
            unsigned m = 1u << (p & 31);
            if (p >= 64)      a2 &= ~m;
            else if (p >= 32) a1 &= ~m;
            else              a0 &= ~m;

            const float* tp = &T[95 - p];
#pragma unroll
            for (int c = 0; c < CH; ++c)
                u[c] += tp[c];
        }

        float so[CH];
#pragma unroll
        for (int c = 0; c < CH; ++c) {
            const int r = c % KR;
            float u_eff = u[c] + pend[r];
            float s = (u_eff >= THETA_V) ? 1.0f : 0.0f;
#pragma unroll
            for (int i = 0; i < KR - 1; ++i)
                pend[(r + 1 + i) % KR] = fmaf(s, rt[i], pend[(r + 1 + i) % KR]);
            pend[r] = s * rt[KR - 1];
            so[c] = s;
        }

        float4* op = (float4*)(orow + ch * CH);
#pragma unroll
        for (int i = 0; i < CH / 4; ++i) {
            float4 v;
            v.x = so[4*i+0]; v.y = so[4*i+1]; v.z = so[4*i+2]; v.w = so[4*i+3];
            op[i] = v;
        }
    }
}

extern "C" void kernel_launch(void* const* d_in, const int* in_sizes, int n_in,
                              void* d_out, int out_size, void* d_ws, size_t ws_size,
                              hipStream_t stream) {
    const float* spike_in = (const float*)d_in[0];
    const float* srm      = (const float*)d_in[1];
    const float* refk     = (const float*)d_in[2];
    float* out = (float*)d_out;

    int srm_len = in_sizes[1];
    int ref_len = in_sizes[2];
    int B = in_sizes[0] / T_LEN;   // 65536 neurons

    const long long N = (long long)B * T_LEN;
    const long long ngroups = (N + 63) / 64;
    // +2 pad words: K1's W3 load at r==0 touches one word past the last used
    const long long packed_words = 4 + 2 * ngroups + 2;
    const size_t need = (size_t)(packed_words + B) * sizeof(unsigned);

    if (d_ws != nullptr && ws_size >= need) {
        unsigned* packed = (unsigned*)d_ws;
        unsigned* flags  = packed + packed_words;
        pack_kernel<<<2048, 256, 0, stream>>>(spike_in, packed, flags,
                                              N, ngroups, B);
        const int tasks = B * NCHUNK;
        conv_flag_kernel<<<(tasks + 255) / 256, 256, 0, stream>>>(
            packed, srm, srm_len, out, flags, B);
        scan_fix_kernel<<<(B + 255) / 256, 256, 0, stream>>>(
            spike_in, srm, srm_len, refk, ref_len, out, flags, B);
    } else {
        int grid = (B + 255) / 256;
        spike_layer_kernel<<<grid, 256, 0, stream>>>(spike_in, srm, srm_len,
                                                     refk, ref_len, out, B);
    }
}

// Round 14
// 160.762 us; speedup vs baseline: 2.0774x; 1.1903x over previous
//
#include <hip/hip_runtime.h>

// SNN spike layer: causal alpha-PSP FIR conv (taps 1..76; srm[0]==0 exactly)
// + sequential refractory threshold scan.
//
// Round-14: IIR upper-bound flagging. R13 proved the 3-dispatch decoupled
// structure (K1 58us conv + pack ~30 + scan ~5). Key insight: K1's u needs
// only a CONSERVATIVE UPPER BOUND, not bit-exactness (K2 recomputes flagged
// rows exactly). srm[j] = (e/10) * j * rho^j (rho = e^-0.1) analytically, so
// the UNTRUNCATED conv obeys a 2-FMA recurrence:
//   A[t] = rho*A[t-1] + rho*x[t-1],  D[t] = rho*D[t-1] + A[t]
//   c*D[t] = sum_{j>=1} srm_model[j] x[t-j]  >=  u_true[t]   (terms >= 0)
// Flag iff c*dmax >= 9.0 (margin ~0.9 covers f32 drift + truncation tail
// <=0.12 + tap tolerance). Soundness for ARBITRARY inputs: each thread
// checks all 77 srm taps against the model (tol 2e-3) and srm_len==77;
// mismatch => flag ALL rows => K2 recomputes everything exactly.
//   K0 pack_zero: coalesced ballot-pack of input bits + coalesced float4
//     zero-fill of the whole output (fold of memset). BW-bound: ~160 MB.
//   K1 flag: 1 thread/neuron, 11-word load + align, fully-unrolled 299-step
//     IIR (bw/bb indices all compile-time -> registers), ~6 VALU/step.
//   K2 scan_fix: verified R10 event-driven conv + sequential scan for
//     flagged rows (compute path end-to-end verified in R10).
// Fallback (ws too small): verified R10 single kernel.
//
// Exactness: unflagged rows provably emit no spikes (ref tail rt<=0 =>
// pend<=0 => u_eff<=u_true<=c*D < 9+margin < theta) -> zeros from K0 are
// exact. Flagged rows fully rewritten by K2's verified exact path.

#define T_LEN 300
#define CH 20
#define NCHUNK 15
#define KS 77              // srm kernel length (alpha, tau=10, eps_tol=0.01)
#define KR 10              // ref kernel tail length (K_ref=11 -> 10 pending)
#define THETA_V 10.0f
#define TSZ 115            // K2 gather table: idx = 95 + c - p

#define RHO_F   0.9048374180359596f   // exp(-0.1)
#define C_E10   0.2718281828459045f   // e/10
#define THR_D   (9.0f / C_E10)        // flag iff D >= 9/c
#define TAP_TOL 2e-3f

// ---------------- K0: bit-pack input + zero output (all coalesced) ----------
__global__ __launch_bounds__(256) void pack_zero_kernel(
    const float* __restrict__ spike_in, unsigned* __restrict__ packed,
    float* __restrict__ out, long long N, long long ngroups)
{
    const int lane = threadIdx.x & 63;
    const long long wid = (long long)blockIdx.x * (blockDim.x >> 6) + (threadIdx.x >> 6);
    const long long nw  = (long long)gridDim.x * (blockDim.x >> 6);
    const long long gtid = (long long)blockIdx.x * blockDim.x + threadIdx.x;
    const long long nthr = (long long)gridDim.x * blockDim.x;

    if (gtid < 4) packed[gtid] = 0u;              // guard words

    // pack: wave reads 64 consecutive floats; bit L of ballot = lane L
    for (long long g = wid; g < ngroups; g += nw) {
        const long long f = g * 64 + lane;
        float x = (f < N) ? spike_in[f] : 0.0f;
        unsigned long long m = __ballot(x != 0.0f);
        if (lane == 0) packed[4 + 2 * g]     = (unsigned)m;
        if (lane == 1) packed[4 + 2 * g + 1] = (unsigned)(m >> 32);
    }

    // zero-fill output, float4 coalesced (N divisible by 4)
    const float4 z = make_float4(0.0f, 0.0f, 0.0f, 0.0f);
    float4* o4 = (float4*)out;
    const long long nf4 = N >> 2;
    for (long long i = gtid; i < nf4; i += nthr) o4[i] = z;
}

// ------------- K1: IIR upper-bound flag (1 thread per neuron) --------------
__global__ __launch_bounds__(256) void flag_kernel(
    const unsigned* __restrict__ packed,
    const float* __restrict__ srm, int srm_len,
    unsigned* __restrict__ flags, int B)
{
    const int n = blockIdx.x * blockDim.x + threadIdx.x;
    if (n >= B) return;

    // model guard: srm must match c*j*rho^j within TAP_TOL (uniform work,
    // scalarized loads). Mismatch -> flag all rows -> K2 exact everywhere.
    bool ok = (srm_len == KS);
    if (ok) {
        ok = fabsf(srm[0]) <= TAP_TOL;
        float pj = 1.0f;
        for (int j = 1; j < KS; ++j) {
            pj *= RHO_F;
            float mj = C_E10 * (float)j * pj;
            ok = ok && (fabsf(srm[j] - mj) <= TAP_TOL);
        }
    }

    // load the row's bit range: flat bits F0 .. F0+299, F0 = 300n.
    // word of flat bit F is packed[4 + (F>>5)], bit F&31 (K0 layout).
    const long long F0 = 300LL * n;
    const int q = 4 + (int)(F0 >> 5);
    const int r = (int)(F0 & 31);
    unsigned W[11];
#pragma unroll
    for (int k = 0; k < 11; ++k) W[k] = packed[q + k];
    unsigned aw[10];                  // aw[k] bit b = row bit 32k + b
#pragma unroll
    for (int k = 0; k < 10; ++k)
        aw[k] = (unsigned)((((unsigned long long)W[k + 1] << 32) | W[k]) >> r);

    // IIR: A[t] = rho*(A[t-1] + x[t-1]); D[t] = rho*D[t-1] + A[t].
    // u_full[t] = c*D[t] >= u_true[t]. Track dmax over t=1..299 (u[0]=0).
    float A = 0.0f, D = 0.0f, dmax = 0.0f;
#pragma unroll
    for (int t = 1; t < T_LEN; ++t) {
        const int bw = (t - 1) >> 5;          // compile-time
        const int bb = (t - 1) & 31;          // compile-time
        // xr = x[t-1] ? rho : 0, branchless: sign-extend bit, AND with rho bits
        int ms = ((int)(aw[bw] << (31 - bb))) >> 31;
        float xr = __int_as_float(ms & __float_as_int(RHO_F));
        A = fmaf(RHO_F, A, xr);
        D = fmaf(RHO_F, D, A);
        dmax = fmaxf(dmax, D);
    }

    flags[n] = (!ok || (dmax >= THR_D)) ? 1u : 0u;
}

// ------------- K2: flagged rows -> verified sequential recompute -----------
__global__ __launch_bounds__(256) void scan_fix_kernel(
    const float* __restrict__ spike_in,
    const float* __restrict__ srm, int srm_len,
    const float* __restrict__ refk, int ref_len,
    float* __restrict__ out, const unsigned* __restrict__ flags, int B)
{
    __shared__ float T[TSZ + 13];
    {
        int k = threadIdx.x;
        if (k < TSZ + 13) {
            int j = k - 19;
            T[k] = (j >= 1 && j < KS && j < srm_len) ? srm[j] : 0.0f;
        }
    }
    __syncthreads();

    int b = blockIdx.x * blockDim.x + threadIdx.x;
    if (b >= B) return;
    if (flags[b] == 0u) return;     // zeros from K0 are exact

    const float* row  = spike_in + (size_t)b * T_LEN;
    float*       orow = out      + (size_t)b * T_LEN;

    float rt[KR];
#pragma unroll
    for (int i = 0; i < KR; ++i) rt[i] = (i + 1 < ref_len) ? refk[i + 1] : 0.0f;
    float pend[KR];
#pragma unroll
    for (int i = 0; i < KR; ++i) pend[i] = 0.0f;

    unsigned w0 = 0, w1 = 0, w2 = 0;
    float nxt[CH];
    {
        const float4* p = (const float4*)row;
#pragma unroll
        for (int i = 0; i < CH / 4; ++i) {
            float4 v = p[i];
            nxt[4*i+0] = v.x; nxt[4*i+1] = v.y; nxt[4*i+2] = v.z; nxt[4*i+3] = v.w;
        }
    }

#pragma unroll 1
    for (int ch = 0; ch < NCHUNK; ++ch) {
        unsigned nb = 0;
#pragma unroll
        for (int i = 0; i < CH; ++i)
            nb |= (nxt[i] != 0.0f) ? (1u << i) : 0u;

        w0 = (w0 >> 20) | (w1 << 12);
        w1 = (w1 >> 20) | (w2 << 12);
        w2 = (w2 >> 20) | (nb << 12);

        if (ch + 1 < NCHUNK) {
            const float4* p = (const float4*)(row + (ch + 1) * CH);
#pragma unroll
            for (int i = 0; i < CH / 4; ++i) {
                float4 v = p[i];
                nxt[4*i+0] = v.x; nxt[4*i+1] = v.y; nxt[4*i+2] = v.z; nxt[4*i+3] = v.w;
            }
        }
        __builtin_amdgcn_sched_barrier(0);

        float u[CH];
#pragma unroll
        for (int c = 0; c < CH; ++c) u[c] = 0.0f;

        unsigned a0 = w0, a1 = w1, a2 = w2;
        while (__ballot(a0 | a1 | a2)) {
            int p = a2 ? (95 - __clz(a2))
                       : (a1 ? (63 - __clz(a1))
                             : (a0 ? (31 - __clz(a0)) : 95));
            unsigned m = 1u << (p & 31);
            if (p >= 64)      a2 &= ~m;
            else if (p >= 32) a1 &= ~m;
            else              a0 &= ~m;

            const float* tp = &T[95 - p];
#pragma unroll
            for (int c = 0; c < CH; ++c)
                u[c] += tp[c];          // == fmaf(srm[j], 1.0f, u[c])
        }

        float so[CH];
#pragma unroll
        for (int c = 0; c < CH; ++c) {
            const int r = c % KR;
            float u_eff = u[c] + pend[r];
            float s = (u_eff >= THETA_V) ? 1.0f : 0.0f;
#pragma unroll
            for (int i = 0; i < KR - 1; ++i)
                pend[(r + 1 + i) % KR] = fmaf(s, rt[i], pend[(r + 1 + i) % KR]);
            pend[r] = s * rt[KR - 1];
            so[c] = s;
        }

        float4* op = (float4*)(orow + ch * CH);
#pragma unroll
        for (int i = 0; i < CH / 4; ++i) {
            float4 v;
            v.x = so[4*i+0]; v.y = so[4*i+1]; v.z = so[4*i+2]; v.w = so[4*i+3];
            op[i] = v;
        }
    }
}

// --------- fallback: round-10 single-kernel path (ws too small) ------------
__global__ __launch_bounds__(256)
__attribute__((amdgpu_waves_per_eu(1, 1)))
void spike_layer_kernel(
    const float* __restrict__ spike_in,
    const float* __restrict__ srm, int srm_len,
    const float* __restrict__ refk, int ref_len,
    float* __restrict__ out, int B)
{
    __shared__ float T[TSZ + 13];
    {
        int k = threadIdx.x;
        if (k < TSZ + 13) {
            int j = k - 19;
            T[k] = (j >= 1 && j < KS && j < srm_len) ? srm[j] : 0.0f;
        }
    }
    __syncthreads();

    int b = blockIdx.x * blockDim.x + threadIdx.x;
    if (b >= B) return;

    const float* row  = spike_in + (size_t)b * T_LEN;
    float*       orow = out      + (size_t)b * T_LEN;

    float rt[KR];
#pragma unroll
    for (int i = 0; i < KR; ++i) rt[i] = (i + 1 < ref_len) ? refk[i + 1] : 0.0f;
    float pend[KR];
#pragma unroll
    for (int i = 0; i < KR; ++i) pend[i] = 0.0f;

    unsigned w0 = 0, w1 = 0, w2 = 0;
    float nxt[CH];
    {
        const float4* p = (const float4*)row;
#pragma unroll
        for (int i = 0; i < CH / 4; ++i) {
            float4 v = p[i];
            nxt[4*i+0] = v.x; nxt[4*i+1] = v.y; nxt[4*i+2] = v.z; nxt[4*i+3] = v.w;
        }
    }

#pragma unroll 1
    for (int ch = 0; ch < NCHUNK; ++ch) {
        unsigned nb = 0;
#pragma unroll
        for (int i = 0; i < CH; ++i)
            nb |= (nxt[i] != 0.0f) ? (1u << i) : 0u;

        w0 = (w0 >> 20) | (w1 << 12);
        w1 = (w1 >> 20) | (w2 << 12);
        w2 = (w2 >> 20) | (nb << 12);

        if (ch + 1 < NCHUNK) {
            const float4* p = (const float4*)(row + (ch + 1) * CH);
#pragma unroll
            for (int i = 0; i < CH / 4; ++i) {
                float4 v = p[i];
                nxt[4*i+0] = v.x; nxt[4*i+1] = v.y; nxt[4*i+2] = v.z; nxt[4*i+3] = v.w;
            }
        }
        __builtin_amdgcn_sched_barrier(0);

        float u[CH];
#pragma unroll
        for (int c = 0; c < CH; ++c) u[c] = 0.0f;

        unsigned a0 = w0, a1 = w1, a2 = w2;
        while (__ballot(a0 | a1 | a2)) {
            int p = a2 ? (95 - __clz(a2))
                       : (a1 ? (63 - __clz(a1))
                             : (a0 ? (31 - __clz(a0)) : 95));
            unsigned m = 1u << (p & 31);
            if (p >= 64)      a2 &= ~m;
            else if (p >= 32) a1 &= ~m;
            else              a0 &= ~m;

            const float* tp = &T[95 - p];
#pragma unroll
            for (int c = 0; c < CH; ++c)
                u[c] += tp[c];
        }

        float so[CH];
#pragma unroll
        for (int c = 0; c < CH; ++c) {
            const int r = c % KR;
            float u_eff = u[c] + pend[r];
            float s = (u_eff >= THETA_V) ? 1.0f : 0.0f;
#pragma unroll
            for (int i = 0; i < KR - 1; ++i)
                pend[(r + 1 + i) % KR] = fmaf(s, rt[i], pend[(r + 1 + i) % KR]);
            pend[r] = s * rt[KR - 1];
            so[c] = s;
        }

        float4* op = (float4*)(orow + ch * CH);
#pragma unroll
        for (int i = 0; i < CH / 4; ++i) {
            float4 v;
            v.x = so[4*i+0]; v.y = so[4*i+1]; v.z = so[4*i+2]; v.w = so[4*i+3];
            op[i] = v;
        }
    }
}

extern "C" void kernel_launch(void* const* d_in, const int* in_sizes, int n_in,
                              void* d_out, int out_size, void* d_ws, size_t ws_size,
                              hipStream_t stream) {
    const float* spike_in = (const float*)d_in[0];
    const float* srm      = (const float*)d_in[1];
    const float* refk     = (const float*)d_in[2];
    float* out = (float*)d_out;

    int srm_len = in_sizes[1];
    int ref_len = in_sizes[2];
    int B = in_sizes[0] / T_LEN;   // 65536 neurons

    const long long N = (long long)B * T_LEN;
    const long long ngroups = (N + 63) / 64;
    const long long packed_words = 4 + 2 * ngroups + 2;   // +2: K1 W[10] slack
    const size_t need = (size_t)(packed_words + B) * sizeof(unsigned);

    if (d_ws != nullptr && ws_size >= need) {
        unsigned* packed = (unsigned*)d_ws;
        unsigned* flags  = packed + packed_words;
        pack_zero_kernel<<<2048, 256, 0, stream>>>(spike_in, packed, out,
                                                   N, ngroups);
        flag_kernel<<<(B + 255) / 256, 256, 0, stream>>>(packed, srm, srm_len,
                                                         flags, B);
        scan_fix_kernel<<<(B + 255) / 256, 256, 0, stream>>>(
            spike_in, srm, srm_len, refk, ref_len, out, flags, B);
    } else {
        int grid = (B + 255) / 256;
        spike_layer_kernel<<<grid, 256, 0, stream>>>(spike_in, srm, srm_len,
                                                     refk, ref_len, out, B);
    }
}

// Round 15
// 158.713 us; speedup vs baseline: 2.1042x; 1.0129x over previous
//
#include <hip/hip_runtime.h>

// SNN spike layer: causal alpha-PSP FIR conv (taps 1..76; srm[0]==0 exactly)
// + sequential refractory threshold scan.
//
// Round-15: BW-tune the last hot kernel. R14 landed the IIR-flag structure
// (160.8us total; pack_zero 50us, flag ~3, scan ~2). pack_zero's counters
// (VGPR=8, VALU 15.7%, 3.2 TB/s logical) show an MLP shortfall: one scalar
// dword load in flight per wave. Fixes:
//   - zero-fill -> hipMemsetAsync(out) (full-BW driver memset; memset on ws
//     proved graph-capture-safe in R11/R12)
//   - pack loop unrolled x4: 4 independent loads issued together (4x MLP
//     -> HBM-saturated), 4 ballots, one 8-lane contiguous 32B store
// flag / scan / fallback kernels unchanged (verified R14/R10).
//
// Structure recap:
//   memset(out)  : zeros are exact for every unflagged row (theorem below)
//   pack_kernel  : coalesced ballot-pack of input bits (2.5 MB, L2-fits)
//   flag_kernel  : 1 thread/neuron IIR upper bound. srm[j] = c*j*rho^j
//     (c=e/10, rho=e^-0.1) analytically; A[t]=rho*(A[t-1]+x[t-1]),
//     D[t]=rho*D[t-1]+A[t] gives c*D[t] = untruncated conv >= u_true[t]
//     (all terms >= 0). Flag iff c*dmax >= 9.0 (covers f32 drift + tail
//     <=0.12 + tap tol). Soundness for ARBITRARY inputs: every thread
//     verifies all 77 taps against the model (tol 2e-3) and srm_len==77;
//     mismatch -> flag ALL rows -> K2 recomputes everything exactly.
//   scan_fix     : flagged rows -> verified R10 event-driven conv +
//     sequential scan (exact path).
// Theorem (exact): ref tail rt[] <= 0 => pend <= 0 => u_eff <= u_true <=
// c*D; unflagged => u_eff < theta everywhere => no spike => zeros exact.
// Fallback (ws too small): verified R10 single kernel.

#define T_LEN 300
#define CH 20
#define NCHUNK 15
#define KS 77              // srm kernel length (alpha, tau=10, eps_tol=0.01)
#define KR 10              // ref kernel tail length (K_ref=11 -> 10 pending)
#define THETA_V 10.0f
#define TSZ 115            // K2 gather table: idx = 95 + c - p

#define RHO_F   0.9048374180359596f   // exp(-0.1)
#define C_E10   0.2718281828459045f   // e/10
#define THR_D   (9.0f / C_E10)        // flag iff D >= 9/c
#define TAP_TOL 2e-3f

// ---------------- K0: bit-pack input, 4x-unrolled ballots ------------------
__global__ __launch_bounds__(256) void pack_kernel(
    const float* __restrict__ spike_in, unsigned* __restrict__ packed,
    long long N, long long ngroups)
{
    const int lane = threadIdx.x & 63;
    const long long wid = (long long)blockIdx.x * (blockDim.x >> 6) + (threadIdx.x >> 6);
    const long long nw  = (long long)gridDim.x * (blockDim.x >> 6);
    const long long gtid = (long long)blockIdx.x * blockDim.x + threadIdx.x;

    if (gtid < 4) packed[gtid] = 0u;              // guard words (bits -128..-1)

    // each wave: 4 consecutive 64-float groups per iteration.
    // 4 independent loads -> 4x memory-level parallelism (R14: one dword
    // in flight per wave capped the kernel at 3.2 of 6.3 TB/s).
    for (long long g = wid * 4; g < ngroups; g += nw * 4) {
        const long long f0 = g * 64 + lane;
        float x0 = (f0           < N) ? spike_in[f0]           : 0.0f;
        float x1 = (f0 + 64      < N) ? spike_in[f0 + 64]      : 0.0f;
        float x2 = (f0 + 128     < N) ? spike_in[f0 + 128]     : 0.0f;
        float x3 = (f0 + 192     < N) ? spike_in[f0 + 192]     : 0.0f;

        unsigned long long m0 = __ballot(x0 != 0.0f);   // bit L = lane L
        unsigned long long m1 = __ballot(x1 != 0.0f);
        unsigned long long m2 = __ballot(x2 != 0.0f);
        unsigned long long m3 = __ballot(x3 != 0.0f);

        // 8 consecutive words [4+2g, 4+2g+8) written by lanes 0..7 (32B
        // contiguous): lane k -> group g+(k>>1), half k&1.
        if (lane < 8) {
            const long long gk = g + (lane >> 1);
            if (gk < ngroups) {
                unsigned long long sel = (lane < 2) ? m0
                                       : (lane < 4) ? m1
                                       : (lane < 6) ? m2 : m3;
                unsigned wv = (lane & 1) ? (unsigned)(sel >> 32) : (unsigned)sel;
                packed[4 + 2 * g + lane] = wv;
            }
        }
    }
}

// ------------- K1: IIR upper-bound flag (1 thread per neuron) --------------
__global__ __launch_bounds__(256) void flag_kernel(
    const unsigned* __restrict__ packed,
    const float* __restrict__ srm, int srm_len,
    unsigned* __restrict__ flags, int B)
{
    const int n = blockIdx.x * blockDim.x + threadIdx.x;
    if (n >= B) return;

    // model guard: srm must match c*j*rho^j within TAP_TOL (uniform work,
    // scalarized loads). Mismatch -> flag all rows -> K2 exact everywhere.
    bool ok = (srm_len == KS);
    if (ok) {
        ok = fabsf(srm[0]) <= TAP_TOL;
        float pj = 1.0f;
        for (int j = 1; j < KS; ++j) {
            pj *= RHO_F;
            float mj = C_E10 * (float)j * pj;
            ok = ok && (fabsf(srm[j] - mj) <= TAP_TOL);
        }
    }

    // load the row's bit range: flat bits F0 .. F0+299, F0 = 300n.
    // word of flat bit F is packed[4 + (F>>5)], bit F&31 (K0 layout).
    const long long F0 = 300LL * n;
    const int q = 4 + (int)(F0 >> 5);
    const int r = (int)(F0 & 31);
    unsigned W[11];
#pragma unroll
    for (int k = 0; k < 11; ++k) W[k] = packed[q + k];
    unsigned aw[10];                  // aw[k] bit b = row bit 32k + b
#pragma unroll
    for (int k = 0; k < 10; ++k)
        aw[k] = (unsigned)((((unsigned long long)W[k + 1] << 32) | W[k]) >> r);

    // IIR: A[t] = rho*(A[t-1] + x[t-1]); D[t] = rho*D[t-1] + A[t].
    // u_full[t] = c*D[t] >= u_true[t]. Track dmax over t=1..299 (u[0]=0).
    float A = 0.0f, D = 0.0f, dmax = 0.0f;
#pragma unroll
    for (int t = 1; t < T_LEN; ++t) {
        const int bw = (t - 1) >> 5;          // compile-time
        const int bb = (t - 1) & 31;          // compile-time
        // xr = x[t-1] ? rho : 0, branchless
        int ms = ((int)(aw[bw] << (31 - bb))) >> 31;
        float xr = __int_as_float(ms & __float_as_int(RHO_F));
        A = fmaf(RHO_F, A, xr);
        D = fmaf(RHO_F, D, A);
        dmax = fmaxf(dmax, D);
    }

    flags[n] = (!ok || (dmax >= THR_D)) ? 1u : 0u;
}

// ------------- K2: flagged rows -> verified sequential recompute -----------
__global__ __launch_bounds__(256) void scan_fix_kernel(
    const float* __restrict__ spike_in,
    const float* __restrict__ srm, int srm_len,
    const float* __restrict__ refk, int ref_len,
    float* __restrict__ out, const unsigned* __restrict__ flags, int B)
{
    __shared__ float T[TSZ + 13];
    {
        int k = threadIdx.x;
        if (k < TSZ + 13) {
            int j = k - 19;
            T[k] = (j >= 1 && j < KS && j < srm_len) ? srm[j] : 0.0f;
        }
    }
    __syncthreads();

    int b = blockIdx.x * blockDim.x + threadIdx.x;
    if (b >= B) return;
    if (flags[b] == 0u) return;     // zeros from memset are exact

    const float* row  = spike_in + (size_t)b * T_LEN;
    float*       orow = out      + (size_t)b * T_LEN;

    float rt[KR];
#pragma unroll
    for (int i = 0; i < KR; ++i) rt[i] = (i + 1 < ref_len) ? refk[i + 1] : 0.0f;
    float pend[KR];
#pragma unroll
    for (int i = 0; i < KR; ++i) pend[i] = 0.0f;

    unsigned w0 = 0, w1 = 0, w2 = 0;
    float nxt[CH];
    {
        const float4* p = (const float4*)row;
#pragma unroll
        for (int i = 0; i < CH / 4; ++i) {
            float4 v = p[i];
            nxt[4*i+0] = v.x; nxt[4*i+1] = v.y; nxt[4*i+2] = v.z; nxt[4*i+3] = v.w;
        }
    }

#pragma unroll 1
    for (int ch = 0; ch < NCHUNK; ++ch) {
        unsigned nb = 0;
#pragma unroll
        for (int i = 0; i < CH; ++i)
            nb |= (nxt[i] != 0.0f) ? (1u << i) : 0u;

        w0 = (w0 >> 20) | (w1 << 12);
        w1 = (w1 >> 20) | (w2 << 12);
        w2 = (w2 >> 20) | (nb << 12);

        if (ch + 1 < NCHUNK) {
            const float4* p = (const float4*)(row + (ch + 1) * CH);
#pragma unroll
            for (int i = 0; i < CH / 4; ++i) {
                float4 v = p[i];
                nxt[4*i+0] = v.x; nxt[4*i+1] = v.y; nxt[4*i+2] = v.z; nxt[4*i+3] = v.w;
            }
        }
        __builtin_amdgcn_sched_barrier(0);

        float u[CH];
#pragma unroll
        for (int c = 0; c < CH; ++c) u[c] = 0.0f;

        unsigned a0 = w0, a1 = w1, a2 = w2;
        while (__ballot(a0 | a1 | a2)) {
            int p = a2 ? (95 - __clz(a2))
                       : (a1 ? (63 - __clz(a1))
                             : (a0 ? (31 - __clz(a0)) : 95));
            unsigned m = 1u << (p & 31);
            if (p >= 64)      a2 &= ~m;
            else if (p >= 32) a1 &= ~m;
            else              a0 &= ~m;

            const float* tp = &T[95 - p];
#pragma unroll
            for (int c = 0; c < CH; ++c)
                u[c] += tp[c];          // == fmaf(srm[j], 1.0f, u[c])
        }

        float so[CH];
#pragma unroll
        for (int c = 0; c < CH; ++c) {
            const int r = c % KR;
            float u_eff = u[c] + pend[r];
            float s = (u_eff >= THETA_V) ? 1.0f : 0.0f;
#pragma unroll
            for (int i = 0; i < KR - 1; ++i)
                pend[(r + 1 + i) % KR] = fmaf(s, rt[i], pend[(r + 1 + i) % KR]);
            pend[r] = s * rt[KR - 1];
            so[c] = s;
        }

        float4* op = (float4*)(orow + ch * CH);
#pragma unroll
        for (int i = 0; i < CH / 4; ++i) {
            float4 v;
            v.x = so[4*i+0]; v.y = so[4*i+1]; v.z = so[4*i+2]; v.w = so[4*i+3];
            op[i] = v;
        }
    }
}

// --------- fallback: round-10 single-kernel path (ws too small) ------------
__global__ __launch_bounds__(256)
__attribute__((amdgpu_waves_per_eu(1, 1)))
void spike_layer_kernel(
    const float* __restrict__ spike_in,
    const float* __restrict__ srm, int srm_len,
    const float* __restrict__ refk, int ref_len,
    float* __restrict__ out, int B)
{
    __shared__ float T[TSZ + 13];
    {
        int k = threadIdx.x;
        if (k < TSZ + 13) {
            int j = k - 19;
            T[k] = (j >= 1 && j < KS && j < srm_len) ? srm[j] : 0.0f;
        }
    }
    __syncthreads();

    int b = blockIdx.x * blockDim.x + threadIdx.x;
    if (b >= B) return;

    const float* row  = spike_in + (size_t)b * T_LEN;
    float*       orow = out      + (size_t)b * T_LEN;

    float rt[KR];
#pragma unroll
    for (int i = 0; i < KR; ++i) rt[i] = (i + 1 < ref_len) ? refk[i + 1] : 0.0f;
    float pend[KR];
#pragma unroll
    for (int i = 0; i < KR; ++i) pend[i] = 0.0f;

    unsigned w0 = 0, w1 = 0, w2 = 0;
    float nxt[CH];
    {
        const float4* p = (const float4*)row;
#pragma unroll
        for (int i = 0; i < CH / 4; ++i) {
            float4 v = p[i];
            nxt[4*i+0] = v.x; nxt[4*i+1] = v.y; nxt[4*i+2] = v.z; nxt[4*i+3] = v.w;
        }
    }

#pragma unroll 1
    for (int ch = 0; ch < NCHUNK; ++ch) {
        unsigned nb = 0;
#pragma unroll
        for (int i = 0; i < CH; ++i)
            nb |= (nxt[i] != 0.0f) ? (1u << i) : 0u;

        w0 = (w0 >> 20) | (w1 << 12);
        w1 = (w1 >> 20) | (w2 << 12);
        w2 = (w2 >> 20) | (nb << 12);

        if (ch + 1 < NCHUNK) {
            const float4* p = (const float4*)(row + (ch + 1) * CH);
#pragma unroll
            for (int i = 0; i < CH / 4; ++i) {
                float4 v = p[i];
                nxt[4*i+0] = v.x; nxt[4*i+1] = v.y; nxt[4*i+2] = v.z; nxt[4*i+3] = v.w;
            }
        }
        __builtin_amdgcn_sched_barrier(0);

        float u[CH];
#pragma unroll
        for (int c = 0; c < CH; ++c) u[c] = 0.0f;

        unsigned a0 = w0, a1 = w1, a2 = w2;
        while (__ballot(a0 | a1 | a2)) {
            int p = a2 ? (95 - __clz(a2))
                       : (a1 ? (63 - __clz(a1))
                             : (a0 ? (31 - __clz(a0)) : 95));
            unsigned m = 1u << (p & 31);
            if (p >= 64)      a2 &= ~m;
            else if (p >= 32) a1 &= ~m;
            else              a0 &= ~m;

            const float* tp = &T[95 - p];
#pragma unroll
            for (int c = 0; c < CH; ++c)
                u[c] += tp[c];
        }

        float so[CH];
#pragma unroll
        for (int c = 0; c < CH; ++c) {
            const int r = c % KR;
            float u_eff = u[c] + pend[r];
            float s = (u_eff >= THETA_V) ? 1.0f : 0.0f;
#pragma unroll
            for (int i = 0; i < KR - 1; ++i)
                pend[(r + 1 + i) % KR] = fmaf(s, rt[i], pend[(r + 1 + i) % KR]);
            pend[r] = s * rt[KR - 1];
            so[c] = s;
        }

        float4* op = (float4*)(orow + ch * CH);
#pragma unroll
        for (int i = 0; i < CH / 4; ++i) {
            float4 v;
            v.x = so[4*i+0]; v.y = so[4*i+1]; v.z = so[4*i+2]; v.w = so[4*i+3];
            op[i] = v;
        }
    }
}

extern "C" void kernel_launch(void* const* d_in, const int* in_sizes, int n_in,
                              void* d_out, int out_size, void* d_ws, size_t ws_size,
                              hipStream_t stream) {
    const float* spike_in = (const float*)d_in[0];
    const float* srm      = (const float*)d_in[1];
    const float* refk     = (const float*)d_in[2];
    float* out = (float*)d_out;

    int srm_len = in_sizes[1];
    int ref_len = in_sizes[2];
    int B = in_sizes[0] / T_LEN;   // 65536 neurons

    const long long N = (long long)B * T_LEN;
    const long long ngroups = (N + 63) / 64;
    const long long packed_words = 4 + 2 * ngroups + 2;   // +2: flag W[10] slack
    const size_t need = (size_t)(packed_words + B) * sizeof(unsigned);

    if (d_ws != nullptr && ws_size >= need) {
        unsigned* packed = (unsigned*)d_ws;
        unsigned* flags  = packed + packed_words;
        // zeros are exact for every unflagged row (theorem in header)
        hipMemsetAsync(out, 0, (size_t)B * T_LEN * sizeof(float), stream);
        pack_kernel<<<2048, 256, 0, stream>>>(spike_in, packed, N, ngroups);
        flag_kernel<<<(B + 255) / 256, 256, 0, stream>>>(packed, srm, srm_len,
                                                         flags, B);
        scan_fix_kernel<<<(B + 255) / 256, 256, 0, stream>>>(
            spike_in, srm, srm_len, refk, ref_len, out, flags, B);
    } else {
        int grid = (B + 255) / 256;
        spike_layer_kernel<<<grid, 256, 0, stream>>>(spike_in, srm, srm_len,
                                                     refk, ref_len, out, B);
    }
}

// Round 16
// 149.871 us; speedup vs baseline: 2.2284x; 1.0590x over previous
//
#include <hip/hip_runtime.h>

// SNN spike layer: causal alpha-PSP FIR conv (taps 1..76; srm[0]==0 exactly)
// + sequential refractory threshold scan.
//
// Round-16: FUSED pack+flag+zero single streaming pass. R15 ledger: fixed
// harness overhead ~95us; our kernel sum ~60us of which pack ~43 (separate
// memset 12, flag 3, scan 2). The input was being read once and the output
// written once, but across 3 dispatches with a 2.5MB bit round-trip and a
// 1-wave/SIMD flag kernel. This build does it all in ONE kernel:
//   - block = 64 neurons (group); 1024 blocks = 4096 waves = 4/SIMD
//   - phase A: thread packs 3 LDS words (word = 32 consecutive floats,
//     8 independent float4 loads -> 8-deep MLP, full line utilization)
//     and writes 19 coalesced zero-float4s of the group's output
//   - phase B: threads 0..63 assemble their row's bits from LDS (funnel
//     shift) and run the VERIFIED 299-step IIR upper bound; write flags
//   total HBM traffic = read 78.6 MB + write 78.9 MB = the floor.
//   ws need = B*4 = 256 KB (flags only).
// scan_fix: flagged rows -> verified R10 event-driven conv + sequential
//   scan (exact). Fallback (ws too small): verified R10 single kernel.
//
// Exactness theorem (all inputs): srm[j] = c*j*rho^j (c=e/10, rho=e^-0.1);
// A[t]=rho*(A[t-1]+x[t-1]), D[t]=rho*D[t-1]+A[t] => c*D[t] = untruncated
// conv >= u_true[t] (all terms >= 0). Ref tail rt[] <= 0 => pend <= 0 =>
// u_eff <= u_true <= c*D. Unflagged (c*dmax < 9 < theta) => no spike =>
// zeros exact. Model guard: all 77 taps checked vs model (tol 2e-3) and
// srm_len==77; mismatch -> flag ALL -> scan_fix recomputes exactly.

#define T_LEN 300
#define CH 20
#define NCHUNK 15
#define KS 77              // srm kernel length (alpha, tau=10, eps_tol=0.01)
#define KR 10              // ref kernel tail length (K_ref=11 -> 10 pending)
#define THETA_V 10.0f
#define TSZ 115            // scan_fix gather table: idx = 95 + c - p

#define RHO_F   0.9048374180359596f   // exp(-0.1)
#define C_E10   0.2718281828459045f   // e/10
#define THR_D   (9.0f / C_E10)        // flag iff D >= 9/c
#define TAP_TOL 2e-3f

#define NPB  64            // neurons per group/block
#define WPG  600           // bit-words per group: 64*300/32
#define F4PG 4800          // float4s per group: 64*300/4

// -------- fused: pack (LDS) + IIR flag + coalesced zero-store --------------
__global__ __launch_bounds__(256) void fused_kernel(
    const float* __restrict__ spike_in,
    const float* __restrict__ srm, int srm_len,
    float* __restrict__ out, unsigned* __restrict__ flags, int B)
{
    __shared__ unsigned Wlds[WPG + 8];

    const int t = threadIdx.x;
    const int g = blockIdx.x;                     // neuron group
    const long long NF     = (long long)B * T_LEN;
    const long long base_f = (long long)NPB * T_LEN * g;   // 19200*g

    // ---- phase A: pack 3 words/thread; word w = group floats [32w,32w+32) --
#pragma unroll
    for (int k = 0; k < 3; ++k) {
        const int w = t + 256 * k;
        if (w < WPG) {
            const long long f0 = base_f + 32LL * w;
            unsigned bits = 0u;
            if (f0 + 32 <= NF) {                  // full word (fast path)
                const float4* p = (const float4*)(spike_in + f0);
#pragma unroll
                for (int i = 0; i < 8; ++i) {     // 8 independent loads
                    float4 v = p[i];
                    bits |= (v.x != 0.0f ? 1u : 0u) << (4 * i + 0);
                    bits |= (v.y != 0.0f ? 1u : 0u) << (4 * i + 1);
                    bits |= (v.z != 0.0f ? 1u : 0u) << (4 * i + 2);
                    bits |= (v.w != 0.0f ? 1u : 0u) << (4 * i + 3);
                }
            } else {                              // partial tail group
                for (int j = 0; j < 32; ++j) {
                    const long long f = f0 + j;
                    float x = (f < NF) ? spike_in[f] : 0.0f;
                    bits |= (x != 0.0f ? 1u : 0u) << j;
                }
            }
            Wlds[w] = bits;
        }
    }
    if (t < 8) Wlds[WPG + t] = 0u;                // funnel-read slack

    // ---- phase A: coalesced zero-store of the group's output region -------
    {
        const float4 z = make_float4(0.0f, 0.0f, 0.0f, 0.0f);
        const long long nf4 = NF >> 2;
        float4* o4 = (float4*)out;
#pragma unroll
        for (int k = 0; k < 19; ++k) {            // 19*256 >= 4800
            const int lw = t + 256 * k;
            if (lw < F4PG) {
                const long long i4 = (long long)F4PG * g + lw;
                if (i4 < nf4) o4[i4] = z;
            }
        }
    }

    __syncthreads();

    // ---- phase B: IIR upper bound, one thread per neuron (verified code) --
    if (t < NPB) {
        const long long neuron = (long long)NPB * g + t;
        if (neuron < B) {
            // model guard: srm must match c*j*rho^j within TAP_TOL.
            bool ok = (srm_len == KS);
            if (ok) {
                ok = fabsf(srm[0]) <= TAP_TOL;
                float pj = 1.0f;
                for (int j = 1; j < KS; ++j) {
                    pj *= RHO_F;
                    float mj = C_E10 * (float)j * pj;
                    ok = ok && (fabsf(srm[j] - mj) <= TAP_TOL);
                }
            }

            // assemble row bits: row t covers group bits [300t, 300t+300)
            const int F0 = T_LEN * t;
            const int q = F0 >> 5;
            const int r = F0 & 31;
            unsigned W[11];
#pragma unroll
            for (int k = 0; k < 11; ++k) W[k] = Wlds[q + k];
            unsigned aw[10];                      // aw[k] bit b = row bit 32k+b
#pragma unroll
            for (int k = 0; k < 10; ++k)
                aw[k] = (unsigned)((((unsigned long long)W[k + 1] << 32) | W[k]) >> r);

            // IIR: A[t]=rho*(A[t-1]+x[t-1]); D[t]=rho*D[t-1]+A[t]
            float A = 0.0f, D = 0.0f, dmax = 0.0f;
#pragma unroll
            for (int tt = 1; tt < T_LEN; ++tt) {
                const int bw = (tt - 1) >> 5;     // compile-time
                const int bb = (tt - 1) & 31;     // compile-time
                int ms = ((int)(aw[bw] << (31 - bb))) >> 31;
                float xr = __int_as_float(ms & __float_as_int(RHO_F));
                A = fmaf(RHO_F, A, xr);
                D = fmaf(RHO_F, D, A);
                dmax = fmaxf(dmax, D);
            }

            flags[neuron] = (!ok || (dmax >= THR_D)) ? 1u : 0u;
        }
    }
}

// ------------- scan_fix: flagged rows -> verified exact recompute ----------
__global__ __launch_bounds__(256) void scan_fix_kernel(
    const float* __restrict__ spike_in,
    const float* __restrict__ srm, int srm_len,
    const float* __restrict__ refk, int ref_len,
    float* __restrict__ out, const unsigned* __restrict__ flags, int B)
{
    __shared__ float T[TSZ + 13];
    {
        int k = threadIdx.x;
        if (k < TSZ + 13) {
            int j = k - 19;
            T[k] = (j >= 1 && j < KS && j < srm_len) ? srm[j] : 0.0f;
        }
    }
    __syncthreads();

    int b = blockIdx.x * blockDim.x + threadIdx.x;
    if (b >= B) return;
    if (flags[b] == 0u) return;     // zeros from fused are exact

    const float* row  = spike_in + (size_t)b * T_LEN;
    float*       orow = out      + (size_t)b * T_LEN;

    float rt[KR];
#pragma unroll
    for (int i = 0; i < KR; ++i) rt[i] = (i + 1 < ref_len) ? refk[i + 1] : 0.0f;
    float pend[KR];
#pragma unroll
    for (int i = 0; i < KR; ++i) pend[i] = 0.0f;

    unsigned w0 = 0, w1 = 0, w2 = 0;
    float nxt[CH];
    {
        const float4* p = (const float4*)row;
#pragma unroll
        for (int i = 0; i < CH / 4; ++i) {
            float4 v = p[i];
            nxt[4*i+0] = v.x; nxt[4*i+1] = v.y; nxt[4*i+2] = v.z; nxt[4*i+3] = v.w;
        }
    }

#pragma unroll 1
    for (int ch = 0; ch < NCHUNK; ++ch) {
        unsigned nb = 0;
#pragma unroll
        for (int i = 0; i < CH; ++i)
            nb |= (nxt[i] != 0.0f) ? (1u << i) : 0u;

        w0 = (w0 >> 20) | (w1 << 12);
        w1 = (w1 >> 20) | (w2 << 12);
        w2 = (w2 >> 20) | (nb << 12);

        if (ch + 1 < NCHUNK) {
            const float4* p = (const float4*)(row + (ch + 1) * CH);
#pragma unroll
            for (int i = 0; i < CH / 4; ++i) {
                float4 v = p[i];
                nxt[4*i+0] = v.x; nxt[4*i+1] = v.y; nxt[4*i+2] = v.z; nxt[4*i+3] = v.w;
            }
        }
        __builtin_amdgcn_sched_barrier(0);

        float u[CH];
#pragma unroll
        for (int c = 0; c < CH; ++c) u[c] = 0.0f;

        unsigned a0 = w0, a1 = w1, a2 = w2;
        while (__ballot(a0 | a1 | a2)) {
            int p = a2 ? (95 - __clz(a2))
                       : (a1 ? (63 - __clz(a1))
                             : (a0 ? (31 - __clz(a0)) : 95));
            unsigned m = 1u << (p & 31);
            if (p >= 64)      a2 &= ~m;
            else if (p >= 32) a1 &= ~m;
            else              a0 &= ~m;

            const float* tp = &T[95 - p];
#pragma unroll
            for (int c = 0; c < CH; ++c)
                u[c] += tp[c];          // == fmaf(srm[j], 1.0f, u[c])
        }

        float so[CH];
#pragma unroll
        for (int c = 0; c < CH; ++c) {
            const int r = c % KR;
            float u_eff = u[c] + pend[r];
            float s = (u_eff >= THETA_V) ? 1.0f : 0.0f;
#pragma unroll
            for (int i = 0; i < KR - 1; ++i)
                pend[(r + 1 + i) % KR] = fmaf(s, rt[i], pend[(r + 1 + i) % KR]);
            pend[r] = s * rt[KR - 1];
            so[c] = s;
        }

        float4* op = (float4*)(orow + ch * CH);
#pragma unroll
        for (int i = 0; i < CH / 4; ++i) {
            float4 v;
            v.x = so[4*i+0]; v.y = so[4*i+1]; v.z = so[4*i+2]; v.w = so[4*i+3];
            op[i] = v;
        }
    }
}

// --------- fallback: round-10 single-kernel path (ws too small) ------------
__global__ __launch_bounds__(256)
__attribute__((amdgpu_waves_per_eu(1, 1)))
void spike_layer_kernel(
    const float* __restrict__ spike_in,
    const float* __restrict__ srm, int srm_len,
    const float* __restrict__ refk, int ref_len,
    float* __restrict__ out, int B)
{
    __shared__ float T[TSZ + 13];
    {
        int k = threadIdx.x;
        if (k < TSZ + 13) {
            int j = k - 19;
            T[k] = (j >= 1 && j < KS && j < srm_len) ? srm[j] : 0.0f;
        }
    }
    __syncthreads();

    int b = blockIdx.x * blockDim.x + threadIdx.x;
    if (b >= B) return;

    const float* row  = spike_in + (size_t)b * T_LEN;
    float*       orow = out      + (size_t)b * T_LEN;

    float rt[KR];
#pragma unroll
    for (int i = 0; i < KR; ++i) rt[i] = (i + 1 < ref_len) ? refk[i + 1] : 0.0f;
    float pend[KR];
#pragma unroll
    for (int i = 0; i < KR; ++i) pend[i] = 0.0f;

    unsigned w0 = 0, w1 = 0, w2 = 0;
    float nxt[CH];
    {
        const float4* p = (const float4*)row;
#pragma unroll
        for (int i = 0; i < CH / 4; ++i) {
            float4 v = p[i];
            nxt[4*i+0] = v.x; nxt[4*i+1] = v.y; nxt[4*i+2] = v.z; nxt[4*i+3] = v.w;
        }
    }

#pragma unroll 1
    for (int ch = 0; ch < NCHUNK; ++ch) {
        unsigned nb = 0;
#pragma unroll
        for (int i = 0; i < CH; ++i)
            nb |= (nxt[i] != 0.0f) ? (1u << i) : 0u;

        w0 = (w0 >> 20) | (w1 << 12);
        w1 = (w1 >> 20) | (w2 << 12);
        w2 = (w2 >> 20) | (nb << 12);

        if (ch + 1 < NCHUNK) {
            const float4* p = (const float4*)(row + (ch + 1) * CH);
#pragma unroll
            for (int i = 0; i < CH / 4; ++i) {
                float4 v = p[i];
                nxt[4*i+0] = v.x; nxt[4*i+1] = v.y; nxt[4*i+2] = v.z; nxt[4*i+3] = v.w;
            }
        }
        __builtin_amdgcn_sched_barrier(0);

        float u[CH];
#pragma unroll
        for (int c = 0; c < CH; ++c) u[c] = 0.0f;

        unsigned a0 = w0, a1 = w1, a2 = w2;
        while (__ballot(a0 | a1 | a2)) {
            int p = a2 ? (95 - __clz(a2))
                       : (a1 ? (63 - __clz(a1))
                             : (a0 ? (31 - __clz(a0)) : 95));
            unsigned m = 1u << (p & 31);
            if (p >= 64)      a2 &= ~m;
            else if (p >= 32) a1 &= ~m;
            else              a0 &= ~m;

            const float* tp = &T[95 - p];
#pragma unroll
            for (int c = 0; c < CH; ++c)
                u[c] += tp[c];
        }

        float so[CH];
#pragma unroll
        for (int c = 0; c < CH; ++c) {
            const int r = c % KR;
            float u_eff = u[c] + pend[r];
            float s = (u_eff >= THETA_V) ? 1.0f : 0.0f;
#pragma unroll
            for (int i = 0; i < KR - 1; ++i)
                pend[(r + 1 + i) % KR] = fmaf(s, rt[i], pend[(r + 1 + i) % KR]);
            pend[r] = s * rt[KR - 1];
            so[c] = s;
        }

        float4* op = (float4*)(orow + ch * CH);
#pragma unroll
        for (int i = 0; i < CH / 4; ++i) {
            float4 v;
            v.x = so[4*i+0]; v.y = so[4*i+1]; v.z = so[4*i+2]; v.w = so[4*i+3];
            op[i] = v;
        }
    }
}

extern "C" void kernel_launch(void* const* d_in, const int* in_sizes, int n_in,
                              void* d_out, int out_size, void* d_ws, size_t ws_size,
                              hipStream_t stream) {
    const float* spike_in = (const float*)d_in[0];
    const float* srm      = (const float*)d_in[1];
    const float* refk     = (const float*)d_in[2];
    float* out = (float*)d_out;

    int srm_len = in_sizes[1];
    int ref_len = in_sizes[2];
    int B = in_sizes[0] / T_LEN;   // 65536 neurons

    const size_t need = (size_t)B * sizeof(unsigned);   // flags only: 256 KB

    if (d_ws != nullptr && ws_size >= need) {
        unsigned* flags = (unsigned*)d_ws;
        const int groups = (B + NPB - 1) / NPB;          // 1024
        fused_kernel<<<groups, 256, 0, stream>>>(spike_in, srm, srm_len,
                                                 out, flags, B);
        scan_fix_kernel<<<(B + 255) / 256, 256, 0, stream>>>(
            spike_in, srm, srm_len, refk, ref_len, out, flags, B);
    } else {
        int grid = (B + 255) / 256;
        spike_layer_kernel<<<grid, 256, 0, stream>>>(spike_in, srm, srm_len,
                                                     refk, ref_len, out, B);
    }
}